// Round 2
// baseline (10528.271 us; speedup 1.0000x reference)
//
#include <hip/hip_runtime.h>
#include <math.h>

// Problem constants
#define DD   256      // word_embd_size
#define TTT  512      // T
#define JJJ  128      // J
#define BBB  32       // B
#define NC   1536     // 6*D combined gate columns (fwd 0..767, bwd 768..1535)
#define ROWS_SRC 16384
#define ROWS_ALL 36864

// ---------------------------------------------------------------------------
// K0: prep — build token table, transposed weights (k-major), concat biases
// ---------------------------------------------------------------------------
__global__ __launch_bounds__(256) void prep_kernel(
    const int* __restrict__ cmnt, const int* __restrict__ src_tok, const int* __restrict__ tgt_tok,
    const float* __restrict__ wih_f, const float* __restrict__ wih_b,
    const float* __restrict__ whh_f, const float* __restrict__ whh_b,
    const float* __restrict__ bih_f, const float* __restrict__ bih_b,
    const float* __restrict__ bhh_f, const float* __restrict__ bhh_b,
    int* __restrict__ tok_all, float* __restrict__ wihT, float* __restrict__ whhT,
    float* __restrict__ bihc, float* __restrict__ bhhc)
{
    const int idx = blockIdx.x * blockDim.x + threadIdx.x;
    const int stride = gridDim.x * blockDim.x;
    for (int i = idx; i < ROWS_ALL; i += stride)
        tok_all[i] = (i < 16384) ? src_tok[i] : (i < 32768) ? tgt_tok[i - 16384] : cmnt[i - 32768];
    for (int i = idx; i < 256 * NC; i += stride) {
        const int k = i / NC, c = i % NC;
        wihT[i] = (c < 768) ? wih_f[(size_t)c * 256 + k] : wih_b[(size_t)(c - 768) * 256 + k];
        whhT[i] = (c < 768) ? whh_f[(size_t)c * 256 + k] : whh_b[(size_t)(c - 768) * 256 + k];
    }
    for (int i = idx; i < NC; i += stride) {
        bihc[i] = (i < 768) ? bih_f[i] : bih_b[i - 768];
        bhhc[i] = (i < 768) ? bhh_f[i] : bhh_b[i - 768];
    }
}

// ---------------------------------------------------------------------------
// K1: gi GEMM — gi[row][c] = sum_k emb[tok[row]][k] * wihT[k][c] + bihc[c]
// Tiles: BM=128, BN=64, BK=16; 256 threads; 8x4 micro-tile
// ---------------------------------------------------------------------------
__global__ __launch_bounds__(256) void gi_gemm(
    const int* __restrict__ tok, int nrows,
    const float* __restrict__ emb, const float* __restrict__ wihT,
    const float* __restrict__ bihc, float* __restrict__ gi)
{
    __shared__ __align__(16) float As[16][132];
    __shared__ __align__(16) float Bs[16][68];
    const int tid = threadIdx.x;
    const int m0 = blockIdx.x * 128;
    const int n0 = blockIdx.y * 64;

    const int ar = tid >> 2;            // 0..63
    const int ak = (tid & 3) << 2;      // 0,4,8,12
    const float* arow0 = emb + (size_t)tok[m0 + ar] * 256 + ak;
    const float* arow1 = emb + (size_t)tok[m0 + ar + 64] * 256 + ak;
    const int bk = tid >> 4;            // 0..15
    const int bn = (tid & 15) << 2;     // 0..60
    const float* bptr = wihT + (size_t)bk * NC + n0 + bn;

    const int ty = tid >> 4;            // m = ty*8
    const int tx = tid & 15;            // n = tx*4
    float acc[8][4];
    #pragma unroll
    for (int i = 0; i < 8; ++i)
        #pragma unroll
        for (int q = 0; q < 4; ++q) acc[i][q] = 0.f;

    for (int k0 = 0; k0 < 256; k0 += 16) {
        const float4 a0 = *(const float4*)(arow0 + k0);
        const float4 a1 = *(const float4*)(arow1 + k0);
        const float4 bv = *(const float4*)(bptr + (size_t)k0 * NC);
        __syncthreads();
        As[ak + 0][ar] = a0.x; As[ak + 1][ar] = a0.y; As[ak + 2][ar] = a0.z; As[ak + 3][ar] = a0.w;
        As[ak + 0][ar + 64] = a1.x; As[ak + 1][ar + 64] = a1.y; As[ak + 2][ar + 64] = a1.z; As[ak + 3][ar + 64] = a1.w;
        *(float4*)&Bs[bk][bn] = bv;
        __syncthreads();
        #pragma unroll
        for (int kk = 0; kk < 16; ++kk) {
            const float4 av0 = *(const float4*)&As[kk][ty * 8];
            const float4 av1 = *(const float4*)&As[kk][ty * 8 + 4];
            const float4 bv4 = *(const float4*)&Bs[kk][tx * 4];
            float a[8] = {av0.x, av0.y, av0.z, av0.w, av1.x, av1.y, av1.z, av1.w};
            float bb[4] = {bv4.x, bv4.y, bv4.z, bv4.w};
            #pragma unroll
            for (int i = 0; i < 8; ++i)
                #pragma unroll
                for (int q = 0; q < 4; ++q) acc[i][q] = fmaf(a[i], bb[q], acc[i][q]);
        }
    }
    const float4 bias = *(const float4*)(bihc + n0 + tx * 4);
    #pragma unroll
    for (int i = 0; i < 8; ++i) {
        const int r = m0 + ty * 8 + i;
        float4 o;
        o.x = acc[i][0] + bias.x; o.y = acc[i][1] + bias.y;
        o.z = acc[i][2] + bias.z; o.w = acc[i][3] + bias.w;
        *(float4*)(gi + (size_t)r * NC + n0 + tx * 4) = o;
    }
}

// ---------------------------------------------------------------------------
// K2: GRU recurrence — REGISTER-RESIDENT WEIGHTS.
// One block per (chain, batch-row): 192 blocks x 1024 threads (16 waves).
//   j = tid&255 (hidden unit), q = tid>>8 (k-quarter of 64).
// Thread (j,q) holds whhT[q*64..q*64+63][{r,z,n}, col j] = 192 fp32 in VGPRs
// (786 KB/block fits the ~2 MB/CU register file; streamed from L2 ONCE).
// Per step: 16 broadcast ds_read_b128 of h + 192 FMAs/thread; quarter
// partials reduced in LDS; gate math on q==0 waves; gi row prefetched.
// ---------------------------------------------------------------------------
__global__ __launch_bounds__(1024) void gru_kernel(
    const float* __restrict__ gi0, const float* __restrict__ gi1, const float* __restrict__ gi2,
    const float* __restrict__ whhT, const float* __restrict__ bhhc,
    float* __restrict__ e_src, float* __restrict__ e_tgt, float* __restrict__ e_cmnt,
    int chain_base)
{
    const int chain = chain_base + (int)(blockIdx.x >> 5);
    const int b = (int)(blockIdx.x & 31);
    const int seq = chain >> 1, dir = chain & 1;
    const int Tlen = (seq == 2) ? JJJ : TTT;
    const float* gi = (seq == 0) ? gi0 : (seq == 1) ? gi1 : gi2;
    float* e = (seq == 0) ? e_src : (seq == 1) ? e_tgt : e_cmnt;

    const int tid = threadIdx.x;
    const int j = tid & 255;
    const int q = tid >> 8;
    const int cb = dir * 768;

    __shared__ float h[256];
    __shared__ float parts[3][4][256];

    // Load this thread's weight slice into registers (one-time L2 stream).
    float wr[64], wz[64], wn[64];
    {
        const float* wb = whhT + (size_t)(q * 64) * NC + cb + j;
        #pragma unroll
        for (int kk = 0; kk < 64; ++kk) {
            wr[kk] = wb[0];
            wz[kk] = wb[256];
            wn[kk] = wb[512];
            wb += NC;
        }
    }
    const float br = bhhc[cb + j];
    const float bz = bhhc[cb + 256 + j];
    const float bn = bhhc[cb + 512 + j];
    if (q == 0) h[j] = 0.f;
    __syncthreads();

    for (int s = 0; s < Tlen; ++s) {
        const int t = dir ? (Tlen - 1 - s) : s;
        const size_t row = (size_t)(b * Tlen + t);

        // gi prefetch by q==0 threads (issued before the FMA loop; consumed after)
        float gr_ = 0.f, gz_ = 0.f, gn_ = 0.f;
        if (q == 0) {
            const float* girow = gi + row * NC + cb;
            gr_ = girow[j]; gz_ = girow[256 + j]; gn_ = girow[512 + j];
        }

        float ar = 0.f, az = 0.f, an = 0.f;
        #pragma unroll
        for (int c = 0; c < 16; ++c) {
            const float4 h4 = *(const float4*)&h[q * 64 + c * 4];   // wave-uniform → broadcast
            ar = fmaf(wr[c * 4 + 0], h4.x, ar);
            az = fmaf(wz[c * 4 + 0], h4.x, az);
            an = fmaf(wn[c * 4 + 0], h4.x, an);
            ar = fmaf(wr[c * 4 + 1], h4.y, ar);
            az = fmaf(wz[c * 4 + 1], h4.y, az);
            an = fmaf(wn[c * 4 + 1], h4.y, an);
            ar = fmaf(wr[c * 4 + 2], h4.z, ar);
            az = fmaf(wz[c * 4 + 2], h4.z, az);
            an = fmaf(wn[c * 4 + 2], h4.z, an);
            ar = fmaf(wr[c * 4 + 3], h4.w, ar);
            az = fmaf(wz[c * 4 + 3], h4.w, az);
            an = fmaf(wn[c * 4 + 3], h4.w, an);
        }
        parts[0][q][j] = ar;
        parts[1][q][j] = az;
        parts[2][q][j] = an;
        __syncthreads();                       // partials visible; h reads done

        if (q == 0) {
            const float sr = parts[0][0][j] + parts[0][1][j] + parts[0][2][j] + parts[0][3][j] + br;
            const float sz = parts[1][0][j] + parts[1][1][j] + parts[1][2][j] + parts[1][3][j] + bz;
            const float sn = parts[2][0][j] + parts[2][1][j] + parts[2][2][j] + parts[2][3][j] + bn;
            const float r = 1.f / (1.f + __expf(-(gr_ + sr)));
            const float z = 1.f / (1.f + __expf(-(gz_ + sz)));
            const float n = tanhf(gn_ + r * sn);
            const float hnew = (1.f - z) * n + z * h[j];
            h[j] = hnew;
            e[row * 512 + (size_t)(dir * 256) + j] = hnew;
        }
        __syncthreads();                       // h updated; parts free for reuse
    }
}

// ---------------------------------------------------------------------------
// K3: S[b,t,j] = sum_d (ctx[b,t,d]*w2[d]) * ec[b,j,d] + action[b,t]*w2[512]
// NT-GEMM per (seq,b): M=512(t) x N=128(j) x K=512. BM=BN=64, BK=16, 4x4 micro.
// ---------------------------------------------------------------------------
__global__ __launch_bounds__(256) void sim_gemm(
    const float* __restrict__ e_src, const float* __restrict__ e_tgt,
    const float* __restrict__ e_cmnt, const float* __restrict__ w2,
    const int* __restrict__ src_action, const int* __restrict__ tgt_action,
    float* __restrict__ S)
{
    const int seq = (int)(blockIdx.z >> 5);
    const int b = (int)(blockIdx.z & 31);
    const int t0 = blockIdx.x * 64;
    const int j0 = blockIdx.y * 64;
    const float* ctx = ((seq == 0) ? e_src : e_tgt) + (size_t)b * 512 * 512;
    const float* ec = e_cmnt + (size_t)b * 128 * 512;
    const int* act = (seq == 0) ? src_action : tgt_action;

    __shared__ __align__(16) float As[16][68];
    __shared__ __align__(16) float Bs[16][68];
    const int tid = threadIdx.x;
    const int lr = tid >> 2;            // 0..63
    const int lk = (tid & 3) << 2;      // 0,4,8,12
    const int ty = tid >> 4, tx = tid & 15;
    float acc[4][4];
    #pragma unroll
    for (int i = 0; i < 4; ++i)
        #pragma unroll
        for (int q = 0; q < 4; ++q) acc[i][q] = 0.f;

    for (int k0 = 0; k0 < 512; k0 += 16) {
        const float4 w4 = *(const float4*)(w2 + k0 + lk);
        const float4 a4 = *(const float4*)(ctx + (size_t)(t0 + lr) * 512 + k0 + lk);
        const float4 b4 = *(const float4*)(ec + (size_t)(j0 + lr) * 512 + k0 + lk);
        __syncthreads();
        As[lk + 0][lr] = a4.x * w4.x; As[lk + 1][lr] = a4.y * w4.y;
        As[lk + 2][lr] = a4.z * w4.z; As[lk + 3][lr] = a4.w * w4.w;
        Bs[lk + 0][lr] = b4.x; Bs[lk + 1][lr] = b4.y;
        Bs[lk + 2][lr] = b4.z; Bs[lk + 3][lr] = b4.w;
        __syncthreads();
        #pragma unroll
        for (int kk = 0; kk < 16; ++kk) {
            const float4 av = *(const float4*)&As[kk][ty * 4];
            const float4 bv = *(const float4*)&Bs[kk][tx * 4];
            float a[4] = {av.x, av.y, av.z, av.w};
            float bb[4] = {bv.x, bv.y, bv.z, bv.w};
            #pragma unroll
            for (int i = 0; i < 4; ++i)
                #pragma unroll
                for (int q = 0; q < 4; ++q) acc[i][q] = fmaf(a[i], bb[q], acc[i][q]);
        }
    }
    const float w2a = w2[512];
    #pragma unroll
    for (int i = 0; i < 4; ++i) {
        const int t = t0 + ty * 4 + i;
        const float aterm = (float)act[b * 512 + t] * w2a;
        float4 o;
        o.x = acc[i][0] + aterm; o.y = acc[i][1] + aterm;
        o.z = acc[i][2] + aterm; o.w = acc[i][3] + aterm;
        *(float4*)(S + ((size_t)((seq * 32 + b) * 512 + t)) * 128 + j0 + tx * 4) = o;
    }
}

// K4: rowmax over j (S rows are contiguous 128 floats)
__global__ __launch_bounds__(256) void rowmax_kernel(const float* __restrict__ S, float* __restrict__ rowmax)
{
    const int i = blockIdx.x * blockDim.x + threadIdx.x;   // seq*16384 + b*512 + t
    if (i >= 32768) return;
    const float* row = S + (size_t)i * 128;
    float m = row[0];
    for (int jj = 1; jj < 128; ++jj) m = fmaxf(m, row[jj]);
    rowmax[i] = m;
}

// K5: softmax over t (512) per (seq,b)
__global__ __launch_bounds__(256) void softmax_kernel(const float* __restrict__ rowmax, float* __restrict__ bw)
{
    const int base = blockIdx.x * 512;
    const int tid = threadIdx.x;
    __shared__ float red[256];
    const float v0 = rowmax[base + tid];
    const float v1 = rowmax[base + 256 + tid];
    red[tid] = fmaxf(v0, v1);
    __syncthreads();
    for (int off = 128; off > 0; off >>= 1) {
        if (tid < off) red[tid] = fmaxf(red[tid], red[tid + off]);
        __syncthreads();
    }
    const float M = red[0];
    __syncthreads();
    const float e0 = __expf(v0 - M), e1 = __expf(v1 - M);
    red[tid] = e0 + e1;
    __syncthreads();
    for (int off = 128; off > 0; off >>= 1) {
        if (tid < off) red[tid] += red[tid + off];
        __syncthreads();
    }
    const float inv = 1.f / red[0];
    bw[base + tid] = e0 * inv;
    bw[base + 256 + tid] = e1 * inv;
}

// K6: outS[seq,b,j] = sum_t bw[seq,b,t] * S[seq,b,t,j]
__global__ __launch_bounds__(256) void weighted_kernel(
    const float* __restrict__ S, const float* __restrict__ bw, float* __restrict__ outS)
{
    const int sb = blockIdx.x;          // seq*32 + b
    const int tid = threadIdx.x;
    const int j = tid & 127, half = tid >> 7;
    const float* Sb = S + (size_t)sb * 512 * 128;
    const float* w = bw + sb * 512;
    float acc = 0.f;
    for (int t = half * 256; t < half * 256 + 256; ++t)
        acc = fmaf(w[t], Sb[(size_t)t * 128 + j], acc);
    __shared__ float red[256];
    red[tid] = acc;
    __syncthreads();
    if (half == 0) outS[sb * 128 + j] = red[j] + red[128 + j];
}

// K7: write S_diff and result into d_out:  out[0..31]=result, out[32..8223]=S_diff
__global__ __launch_bounds__(256) void final_kernel(
    const float* __restrict__ outS, const float* __restrict__ rank_w,
    const float* __restrict__ rank_b, float* __restrict__ out)
{
    const int tid = threadIdx.x;
    for (int q = tid; q < 8192; q += 256) {
        const int b = q >> 8, c = q & 255;
        out[32 + q] = (c < 128) ? outS[b * 128 + c] : outS[4096 + b * 128 + (c - 128)];
    }
    if (tid < 32) {
        float acc = rank_b[0];
        for (int c = 0; c < 128; ++c) acc = fmaf(outS[tid * 128 + c], rank_w[c], acc);
        for (int c = 0; c < 128; ++c) acc = fmaf(outS[4096 + tid * 128 + c], rank_w[128 + c], acc);
        out[tid] = acc;
    }
}

// ---------------------------------------------------------------------------
extern "C" void kernel_launch(void* const* d_in, const int* in_sizes, int n_in,
                              void* d_out, int out_size, void* d_ws, size_t ws_size,
                              hipStream_t stream)
{
    const int* cmnt       = (const int*)d_in[0];
    const int* src_token  = (const int*)d_in[1];
    const int* tgt_token  = (const int*)d_in[2];
    const int* src_action = (const int*)d_in[3];
    const int* tgt_action = (const int*)d_in[4];
    const float* emb    = (const float*)d_in[5];
    const float* wih_f  = (const float*)d_in[6];
    const float* whh_f  = (const float*)d_in[7];
    const float* bih_f  = (const float*)d_in[8];
    const float* bhh_f  = (const float*)d_in[9];
    const float* wih_b  = (const float*)d_in[10];
    const float* whh_b  = (const float*)d_in[11];
    const float* bih_b  = (const float*)d_in[12];
    const float* bhh_b  = (const float*)d_in[13];
    const float* w2     = (const float*)d_in[14];
    const float* rank_w = (const float*)d_in[15];
    const float* rank_b = (const float*)d_in[16];
    float* out = (float*)d_out;

    float* ws = (float*)d_ws;
    size_t off = 0;
    int*   tok_all = (int*)(ws + off); off += 36864;
    float* wihT   = ws + off; off += 393216;
    float* whhT   = ws + off; off += 393216;
    float* bihc   = ws + off; off += 1536;
    float* bhhc   = ws + off; off += 1536;
    float* rowmax = ws + off; off += 32768;
    float* bw     = ws + off; off += 32768;
    float* outS   = ws + off; off += 8192;
    float* e_src  = ws + off; off += 8388608;
    float* e_tgt  = ws + off; off += 8388608;
    float* e_cmnt = ws + off; off += 2097152;
    float* S      = ws + off; off += 4194304;
    float* gi     = ws + off;
    const size_t avail = ws_size / 4 - off;
    const bool planP = avail >= 56623104ULL;   // gi for all 36864 rows at once

    hipLaunchKernelGGL(prep_kernel, dim3(512), dim3(256), 0, stream,
        cmnt, src_token, tgt_token, wih_f, wih_b, whh_f, whh_b,
        bih_f, bih_b, bhh_f, bhh_b, tok_all, wihT, whhT, bihc, bhhc);

    if (planP) {
        hipLaunchKernelGGL(gi_gemm, dim3(288, 24), dim3(256), 0, stream,
            tok_all, 36864, emb, wihT, bihc, gi);
        hipLaunchKernelGGL(gru_kernel, dim3(192), dim3(1024), 0, stream,
            gi, gi + (size_t)16384 * NC, gi + (size_t)32768 * NC,
            whhT, bhhc, e_src, e_tgt, e_cmnt, 0);
    } else {
        // Serial fallback: reuse a single gi buffer per sequence
        hipLaunchKernelGGL(gi_gemm, dim3(128, 24), dim3(256), 0, stream,
            tok_all, 16384, emb, wihT, bihc, gi);
        hipLaunchKernelGGL(gru_kernel, dim3(64), dim3(1024), 0, stream,
            gi, gi, gi, whhT, bhhc, e_src, e_tgt, e_cmnt, 0);
        hipLaunchKernelGGL(gi_gemm, dim3(128, 24), dim3(256), 0, stream,
            tok_all + 16384, 16384, emb, wihT, bihc, gi);
        hipLaunchKernelGGL(gru_kernel, dim3(64), dim3(1024), 0, stream,
            gi, gi, gi, whhT, bhhc, e_src, e_tgt, e_cmnt, 2);
        hipLaunchKernelGGL(gi_gemm, dim3(32, 24), dim3(256), 0, stream,
            tok_all + 32768, 4096, emb, wihT, bihc, gi);
        hipLaunchKernelGGL(gru_kernel, dim3(64), dim3(1024), 0, stream,
            gi, gi, gi, whhT, bhhc, e_src, e_tgt, e_cmnt, 4);
    }

    hipLaunchKernelGGL(sim_gemm, dim3(8, 2, 64), dim3(256), 0, stream,
        e_src, e_tgt, e_cmnt, w2, src_action, tgt_action, S);
    hipLaunchKernelGGL(rowmax_kernel, dim3(128), dim3(256), 0, stream, S, rowmax);
    hipLaunchKernelGGL(softmax_kernel, dim3(64), dim3(256), 0, stream, rowmax, bw);
    hipLaunchKernelGGL(weighted_kernel, dim3(64), dim3(256), 0, stream, S, bw, outS);
    hipLaunchKernelGGL(final_kernel, dim3(1), dim3(256), 0, stream, outS, rank_w, rank_b, out);
}

// Round 3
// 2150.646 us; speedup vs baseline: 4.8954x; 4.8954x over previous
//
#include <hip/hip_runtime.h>
#include <math.h>

// Problem constants
#define DD   256      // word_embd_size
#define TTT  512      // T
#define JJJ  128      // J
#define BBB  32       // B
#define NC   1536     // 6*D combined gate columns (fwd 0..767, bwd 768..1535)
#define ROWS_SRC 16384
#define ROWS_ALL 36864

typedef _Float16 v2h __attribute__((ext_vector_type(2)));

#if __has_builtin(__builtin_amdgcn_fdot2)
#define FDOT2(a, b, c) __builtin_amdgcn_fdot2((a), (b), (c), false)
#else
#define FDOT2(a, b, c) ((float)(a)[0] * (float)(b)[0] + ((float)(a)[1] * (float)(b)[1] + (c)))
#endif

// ---------------------------------------------------------------------------
// K0: prep — build token table, transposed weights (k-major), concat biases
// ---------------------------------------------------------------------------
__global__ __launch_bounds__(256) void prep_kernel(
    const int* __restrict__ cmnt, const int* __restrict__ src_tok, const int* __restrict__ tgt_tok,
    const float* __restrict__ wih_f, const float* __restrict__ wih_b,
    const float* __restrict__ whh_f, const float* __restrict__ whh_b,
    const float* __restrict__ bih_f, const float* __restrict__ bih_b,
    const float* __restrict__ bhh_f, const float* __restrict__ bhh_b,
    int* __restrict__ tok_all, float* __restrict__ wihT, float* __restrict__ whhT,
    float* __restrict__ bihc, float* __restrict__ bhhc)
{
    const int idx = blockIdx.x * blockDim.x + threadIdx.x;
    const int stride = gridDim.x * blockDim.x;
    for (int i = idx; i < ROWS_ALL; i += stride)
        tok_all[i] = (i < 16384) ? src_tok[i] : (i < 32768) ? tgt_tok[i - 16384] : cmnt[i - 32768];
    for (int i = idx; i < 256 * NC; i += stride) {
        const int k = i / NC, c = i % NC;
        wihT[i] = (c < 768) ? wih_f[(size_t)c * 256 + k] : wih_b[(size_t)(c - 768) * 256 + k];
        whhT[i] = (c < 768) ? whh_f[(size_t)c * 256 + k] : whh_b[(size_t)(c - 768) * 256 + k];
    }
    for (int i = idx; i < NC; i += stride) {
        bihc[i] = (i < 768) ? bih_f[i] : bih_b[i - 768];
        bhhc[i] = (i < 768) ? bhh_f[i] : bhh_b[i - 768];
    }
}

// ---------------------------------------------------------------------------
// K1: gi GEMM — gi[row][c] = sum_k emb[tok[row]][k] * wihT[k][c] + bihc[c]
// Tiles: BM=128, BN=64, BK=16; 256 threads; 8x4 micro-tile
// ---------------------------------------------------------------------------
__global__ __launch_bounds__(256) void gi_gemm(
    const int* __restrict__ tok, int nrows,
    const float* __restrict__ emb, const float* __restrict__ wihT,
    const float* __restrict__ bihc, float* __restrict__ gi)
{
    __shared__ __align__(16) float As[16][132];
    __shared__ __align__(16) float Bs[16][68];
    const int tid = threadIdx.x;
    const int m0 = blockIdx.x * 128;
    const int n0 = blockIdx.y * 64;

    const int ar = tid >> 2;            // 0..63
    const int ak = (tid & 3) << 2;      // 0,4,8,12
    const float* arow0 = emb + (size_t)tok[m0 + ar] * 256 + ak;
    const float* arow1 = emb + (size_t)tok[m0 + ar + 64] * 256 + ak;
    const int bk = tid >> 4;            // 0..15
    const int bn = (tid & 15) << 2;     // 0..60
    const float* bptr = wihT + (size_t)bk * NC + n0 + bn;

    const int ty = tid >> 4;            // m = ty*8
    const int tx = tid & 15;            // n = tx*4
    float acc[8][4];
    #pragma unroll
    for (int i = 0; i < 8; ++i)
        #pragma unroll
        for (int q = 0; q < 4; ++q) acc[i][q] = 0.f;

    for (int k0 = 0; k0 < 256; k0 += 16) {
        const float4 a0 = *(const float4*)(arow0 + k0);
        const float4 a1 = *(const float4*)(arow1 + k0);
        const float4 bv = *(const float4*)(bptr + (size_t)k0 * NC);
        __syncthreads();
        As[ak + 0][ar] = a0.x; As[ak + 1][ar] = a0.y; As[ak + 2][ar] = a0.z; As[ak + 3][ar] = a0.w;
        As[ak + 0][ar + 64] = a1.x; As[ak + 1][ar + 64] = a1.y; As[ak + 2][ar + 64] = a1.z; As[ak + 3][ar + 64] = a1.w;
        *(float4*)&Bs[bk][bn] = bv;
        __syncthreads();
        #pragma unroll
        for (int kk = 0; kk < 16; ++kk) {
            const float4 av0 = *(const float4*)&As[kk][ty * 8];
            const float4 av1 = *(const float4*)&As[kk][ty * 8 + 4];
            const float4 bv4 = *(const float4*)&Bs[kk][tx * 4];
            float a[8] = {av0.x, av0.y, av0.z, av0.w, av1.x, av1.y, av1.z, av1.w};
            float bb[4] = {bv4.x, bv4.y, bv4.z, bv4.w};
            #pragma unroll
            for (int i = 0; i < 8; ++i)
                #pragma unroll
                for (int q = 0; q < 4; ++q) acc[i][q] = fmaf(a[i], bb[q], acc[i][q]);
        }
    }
    const float4 bias = *(const float4*)(bihc + n0 + tx * 4);
    #pragma unroll
    for (int i = 0; i < 8; ++i) {
        const int r = m0 + ty * 8 + i;
        float4 o;
        o.x = acc[i][0] + bias.x; o.y = acc[i][1] + bias.y;
        o.z = acc[i][2] + bias.z; o.w = acc[i][3] + bias.w;
        *(float4*)(gi + (size_t)r * NC + n0 + tx * 4) = o;
    }
}

// ---------------------------------------------------------------------------
// K2: GRU recurrence — fp16-PACKED REGISTER-RESIDENT WEIGHTS.
// One block per (chain, batch-row): 192 blocks x 512 threads (8 waves).
//   j = tid&255 (hidden unit), q = tid>>8 (k-half of 128).
// Thread (j,q) holds whhT[q*128..+127][{r,z,n}, col j] as 192 packed half2
// VGPRs (384 fp16). 8 waves x ~225 VGPR = 1800 < 2048/CU pool -> no spill.
// h: fp32 in a register of the owning q==0 thread; republished per step as
// half2[128] in LDS (wave-uniform broadcast reads in the dot loop).
// Per step: 16 ds_read_b128 + 192 v_dot2_f32_f16 per thread, LDS reduction
// of the two k-halves, gate math on q==0, 2 barriers.
// ---------------------------------------------------------------------------
__global__ __launch_bounds__(512, 2) void gru_kernel(
    const float* __restrict__ gi0, const float* __restrict__ gi1, const float* __restrict__ gi2,
    const float* __restrict__ whhT, const float* __restrict__ bhhc,
    float* __restrict__ e_src, float* __restrict__ e_tgt, float* __restrict__ e_cmnt,
    int chain_base)
{
    const int chain = chain_base + (int)(blockIdx.x >> 5);
    const int b = (int)(blockIdx.x & 31);
    const int seq = chain >> 1, dir = chain & 1;
    const int Tlen = (seq == 2) ? JJJ : TTT;
    const float* gi = (seq == 0) ? gi0 : (seq == 1) ? gi1 : gi2;
    float* e = (seq == 0) ? e_src : (seq == 1) ? e_tgt : e_cmnt;

    const int tid = threadIdx.x;
    const int j = tid & 255;
    const int q = tid >> 8;
    const int cb = dir * 768;

    __shared__ __align__(16) v2h h2s[128];
    __shared__ float parts[3][256];

    // One-time weight load: fp32 from L2, packed to half2 registers.
    v2h wr2[64], wz2[64], wn2[64];
    {
        const float* wb = whhT + (size_t)(q * 128) * NC + cb + j;
        #pragma unroll
        for (int p = 0; p < 64; ++p) {
            v2h a, bzv, c;
            a[0]   = (_Float16)wb[0];        a[1]   = (_Float16)wb[NC];
            bzv[0] = (_Float16)wb[256];      bzv[1] = (_Float16)wb[NC + 256];
            c[0]   = (_Float16)wb[512];      c[1]   = (_Float16)wb[NC + 512];
            wr2[p] = a; wz2[p] = bzv; wn2[p] = c;
            wb += 2 * NC;
        }
    }
    const float br  = bhhc[cb + j];
    const float bzb = bhhc[cb + 256 + j];
    const float bnb = bhhc[cb + 512 + j];

    float hprev = 0.f;                      // q==0 thread j owns h[j]
    if (q == 0 && (j & 1) == 0) {
        v2h z0; z0[0] = (_Float16)0.f; z0[1] = (_Float16)0.f;
        h2s[j >> 1] = z0;
    }
    __syncthreads();

    const int t0i = dir ? (Tlen - 1) : 0;
    const long tstep = dir ? -1 : 1;
    const float* girow = gi + (size_t)(b * Tlen + t0i) * NC + cb;
    float* eptr = e + (size_t)(b * Tlen + t0i) * 512 + (dir << 8) + j;
    const long gstep = tstep * NC;
    const long estep = tstep * 512;

    for (int s = 0; s < Tlen; ++s) {
        // gi prefetch (q==0 consumers) issued before the dot loop
        float gr_ = 0.f, gz_ = 0.f, gn_ = 0.f;
        if (q == 0) { gr_ = girow[j]; gz_ = girow[256 + j]; gn_ = girow[512 + j]; }

        float ar = 0.f, az = 0.f, an = 0.f;
        const v2h* hbase = &h2s[q * 64];
        #pragma unroll
        for (int c = 0; c < 16; ++c) {
            union { float4 f; v2h h[4]; } U;
            U.f = *(const float4*)&hbase[c * 4];
            #pragma unroll
            for (int p = 0; p < 4; ++p) {
                ar = FDOT2(wr2[c * 4 + p], U.h[p], ar);
                az = FDOT2(wz2[c * 4 + p], U.h[p], az);
                an = FDOT2(wn2[c * 4 + p], U.h[p], an);
            }
        }
        if (q == 1) { parts[0][j] = ar; parts[1][j] = az; parts[2][j] = an; }
        __syncthreads();                    // partials visible; all h2s reads done

        if (q == 0) {
            const float sr = ar + parts[0][j] + br;
            const float sz = az + parts[1][j] + bzb;
            const float sn = an + parts[2][j] + bnb;
            const float r = 1.f / (1.f + __expf(-(gr_ + sr)));
            const float z = 1.f / (1.f + __expf(-(gz_ + sz)));
            const float n = tanhf(gn_ + r * sn);
            const float hnew = (1.f - z) * n + z * hprev;
            hprev = hnew;
            *eptr = hnew;
            const float hnb = __shfl_xor(hnew, 1);   // neighbor j^1 (same wave)
            if ((j & 1) == 0) {
                v2h hv; hv[0] = (_Float16)hnew; hv[1] = (_Float16)hnb;
                h2s[j >> 1] = hv;
            }
        }
        girow += gstep;
        eptr += estep;
        __syncthreads();                    // h2s updated before next reads
    }
}

// ---------------------------------------------------------------------------
// K3: S[b,t,j] = sum_d (ctx[b,t,d]*w2[d]) * ec[b,j,d] + action[b,t]*w2[512]
// NT-GEMM per (seq,b): M=512(t) x N=128(j) x K=512. BM=BN=64, BK=16, 4x4 micro.
// ---------------------------------------------------------------------------
__global__ __launch_bounds__(256) void sim_gemm(
    const float* __restrict__ e_src, const float* __restrict__ e_tgt,
    const float* __restrict__ e_cmnt, const float* __restrict__ w2,
    const int* __restrict__ src_action, const int* __restrict__ tgt_action,
    float* __restrict__ S)
{
    const int seq = (int)(blockIdx.z >> 5);
    const int b = (int)(blockIdx.z & 31);
    const int t0 = blockIdx.x * 64;
    const int j0 = blockIdx.y * 64;
    const float* ctx = ((seq == 0) ? e_src : e_tgt) + (size_t)b * 512 * 512;
    const float* ec = e_cmnt + (size_t)b * 128 * 512;
    const int* act = (seq == 0) ? src_action : tgt_action;

    __shared__ __align__(16) float As[16][68];
    __shared__ __align__(16) float Bs[16][68];
    const int tid = threadIdx.x;
    const int lr = tid >> 2;            // 0..63
    const int lk = (tid & 3) << 2;      // 0,4,8,12
    const int ty = tid >> 4, tx = tid & 15;
    float acc[4][4];
    #pragma unroll
    for (int i = 0; i < 4; ++i)
        #pragma unroll
        for (int q = 0; q < 4; ++q) acc[i][q] = 0.f;

    for (int k0 = 0; k0 < 512; k0 += 16) {
        const float4 w4 = *(const float4*)(w2 + k0 + lk);
        const float4 a4 = *(const float4*)(ctx + (size_t)(t0 + lr) * 512 + k0 + lk);
        const float4 b4 = *(const float4*)(ec + (size_t)(j0 + lr) * 512 + k0 + lk);
        __syncthreads();
        As[lk + 0][lr] = a4.x * w4.x; As[lk + 1][lr] = a4.y * w4.y;
        As[lk + 2][lr] = a4.z * w4.z; As[lk + 3][lr] = a4.w * w4.w;
        Bs[lk + 0][lr] = b4.x; Bs[lk + 1][lr] = b4.y;
        Bs[lk + 2][lr] = b4.z; Bs[lk + 3][lr] = b4.w;
        __syncthreads();
        #pragma unroll
        for (int kk = 0; kk < 16; ++kk) {
            const float4 av = *(const float4*)&As[kk][ty * 4];
            const float4 bv = *(const float4*)&Bs[kk][tx * 4];
            float a[4] = {av.x, av.y, av.z, av.w};
            float bb[4] = {bv.x, bv.y, bv.z, bv.w};
            #pragma unroll
            for (int i = 0; i < 4; ++i)
                #pragma unroll
                for (int q = 0; q < 4; ++q) acc[i][q] = fmaf(a[i], bb[q], acc[i][q]);
        }
    }
    const float w2a = w2[512];
    #pragma unroll
    for (int i = 0; i < 4; ++i) {
        const int t = t0 + ty * 4 + i;
        const float aterm = (float)act[b * 512 + t] * w2a;
        float4 o;
        o.x = acc[i][0] + aterm; o.y = acc[i][1] + aterm;
        o.z = acc[i][2] + aterm; o.w = acc[i][3] + aterm;
        *(float4*)(S + ((size_t)((seq * 32 + b) * 512 + t)) * 128 + j0 + tx * 4) = o;
    }
}

// K4: rowmax over j (S rows are contiguous 128 floats)
__global__ __launch_bounds__(256) void rowmax_kernel(const float* __restrict__ S, float* __restrict__ rowmax)
{
    const int i = blockIdx.x * blockDim.x + threadIdx.x;   // seq*16384 + b*512 + t
    if (i >= 32768) return;
    const float* row = S + (size_t)i * 128;
    float m = row[0];
    for (int jj = 1; jj < 128; ++jj) m = fmaxf(m, row[jj]);
    rowmax[i] = m;
}

// K5: softmax over t (512) per (seq,b)
__global__ __launch_bounds__(256) void softmax_kernel(const float* __restrict__ rowmax, float* __restrict__ bw)
{
    const int base = blockIdx.x * 512;
    const int tid = threadIdx.x;
    __shared__ float red[256];
    const float v0 = rowmax[base + tid];
    const float v1 = rowmax[base + 256 + tid];
    red[tid] = fmaxf(v0, v1);
    __syncthreads();
    for (int off = 128; off > 0; off >>= 1) {
        if (tid < off) red[tid] = fmaxf(red[tid], red[tid + off]);
        __syncthreads();
    }
    const float M = red[0];
    __syncthreads();
    const float e0 = __expf(v0 - M), e1 = __expf(v1 - M);
    red[tid] = e0 + e1;
    __syncthreads();
    for (int off = 128; off > 0; off >>= 1) {
        if (tid < off) red[tid] += red[tid + off];
        __syncthreads();
    }
    const float inv = 1.f / red[0];
    bw[base + tid] = e0 * inv;
    bw[base + 256 + tid] = e1 * inv;
}

// K6: outS[seq,b,j] = sum_t bw[seq,b,t] * S[seq,b,t,j]
__global__ __launch_bounds__(256) void weighted_kernel(
    const float* __restrict__ S, const float* __restrict__ bw, float* __restrict__ outS)
{
    const int sb = blockIdx.x;          // seq*32 + b
    const int tid = threadIdx.x;
    const int j = tid & 127, half = tid >> 7;
    const float* Sb = S + (size_t)sb * 512 * 128;
    const float* w = bw + sb * 512;
    float acc = 0.f;
    for (int t = half * 256; t < half * 256 + 256; ++t)
        acc = fmaf(w[t], Sb[(size_t)t * 128 + j], acc);
    __shared__ float red[256];
    red[tid] = acc;
    __syncthreads();
    if (half == 0) outS[sb * 128 + j] = red[j] + red[128 + j];
}

// K7: write S_diff and result into d_out:  out[0..31]=result, out[32..8223]=S_diff
__global__ __launch_bounds__(256) void final_kernel(
    const float* __restrict__ outS, const float* __restrict__ rank_w,
    const float* __restrict__ rank_b, float* __restrict__ out)
{
    const int tid = threadIdx.x;
    for (int q = tid; q < 8192; q += 256) {
        const int b = q >> 8, c = q & 255;
        out[32 + q] = (c < 128) ? outS[b * 128 + c] : outS[4096 + b * 128 + (c - 128)];
    }
    if (tid < 32) {
        float acc = rank_b[0];
        for (int c = 0; c < 128; ++c) acc = fmaf(outS[tid * 128 + c], rank_w[c], acc);
        for (int c = 0; c < 128; ++c) acc = fmaf(outS[4096 + tid * 128 + c], rank_w[128 + c], acc);
        out[tid] = acc;
    }
}

// ---------------------------------------------------------------------------
extern "C" void kernel_launch(void* const* d_in, const int* in_sizes, int n_in,
                              void* d_out, int out_size, void* d_ws, size_t ws_size,
                              hipStream_t stream)
{
    const int* cmnt       = (const int*)d_in[0];
    const int* src_token  = (const int*)d_in[1];
    const int* tgt_token  = (const int*)d_in[2];
    const int* src_action = (const int*)d_in[3];
    const int* tgt_action = (const int*)d_in[4];
    const float* emb    = (const float*)d_in[5];
    const float* wih_f  = (const float*)d_in[6];
    const float* whh_f  = (const float*)d_in[7];
    const float* bih_f  = (const float*)d_in[8];
    const float* bhh_f  = (const float*)d_in[9];
    const float* wih_b  = (const float*)d_in[10];
    const float* whh_b  = (const float*)d_in[11];
    const float* bih_b  = (const float*)d_in[12];
    const float* bhh_b  = (const float*)d_in[13];
    const float* w2     = (const float*)d_in[14];
    const float* rank_w = (const float*)d_in[15];
    const float* rank_b = (const float*)d_in[16];
    float* out = (float*)d_out;

    float* ws = (float*)d_ws;
    size_t off = 0;
    int*   tok_all = (int*)(ws + off); off += 36864;
    float* wihT   = ws + off; off += 393216;
    float* whhT   = ws + off; off += 393216;
    float* bihc   = ws + off; off += 1536;
    float* bhhc   = ws + off; off += 1536;
    float* rowmax = ws + off; off += 32768;
    float* bw     = ws + off; off += 32768;
    float* outS   = ws + off; off += 8192;
    float* e_src  = ws + off; off += 8388608;
    float* e_tgt  = ws + off; off += 8388608;
    float* e_cmnt = ws + off; off += 2097152;
    float* S      = ws + off; off += 4194304;
    float* gi     = ws + off;
    const size_t avail = ws_size / 4 - off;
    const bool planP = avail >= 56623104ULL;   // gi for all 36864 rows at once

    hipLaunchKernelGGL(prep_kernel, dim3(512), dim3(256), 0, stream,
        cmnt, src_token, tgt_token, wih_f, wih_b, whh_f, whh_b,
        bih_f, bih_b, bhh_f, bhh_b, tok_all, wihT, whhT, bihc, bhhc);

    if (planP) {
        hipLaunchKernelGGL(gi_gemm, dim3(288, 24), dim3(256), 0, stream,
            tok_all, 36864, emb, wihT, bihc, gi);
        hipLaunchKernelGGL(gru_kernel, dim3(192), dim3(512), 0, stream,
            gi, gi + (size_t)16384 * NC, gi + (size_t)32768 * NC,
            whhT, bhhc, e_src, e_tgt, e_cmnt, 0);
    } else {
        // Serial fallback: reuse a single gi buffer per sequence
        hipLaunchKernelGGL(gi_gemm, dim3(128, 24), dim3(256), 0, stream,
            tok_all, 16384, emb, wihT, bihc, gi);
        hipLaunchKernelGGL(gru_kernel, dim3(64), dim3(512), 0, stream,
            gi, gi, gi, whhT, bhhc, e_src, e_tgt, e_cmnt, 0);
        hipLaunchKernelGGL(gi_gemm, dim3(128, 24), dim3(256), 0, stream,
            tok_all + 16384, 16384, emb, wihT, bihc, gi);
        hipLaunchKernelGGL(gru_kernel, dim3(64), dim3(512), 0, stream,
            gi, gi, gi, whhT, bhhc, e_src, e_tgt, e_cmnt, 2);
        hipLaunchKernelGGL(gi_gemm, dim3(32, 24), dim3(256), 0, stream,
            tok_all + 32768, 4096, emb, wihT, bihc, gi);
        hipLaunchKernelGGL(gru_kernel, dim3(64), dim3(512), 0, stream,
            gi, gi, gi, whhT, bhhc, e_src, e_tgt, e_cmnt, 4);
    }

    hipLaunchKernelGGL(sim_gemm, dim3(8, 2, 64), dim3(256), 0, stream,
        e_src, e_tgt, e_cmnt, w2, src_action, tgt_action, S);
    hipLaunchKernelGGL(rowmax_kernel, dim3(128), dim3(256), 0, stream, S, rowmax);
    hipLaunchKernelGGL(softmax_kernel, dim3(64), dim3(256), 0, stream, rowmax, bw);
    hipLaunchKernelGGL(weighted_kernel, dim3(64), dim3(256), 0, stream, S, bw, outS);
    hipLaunchKernelGGL(final_kernel, dim3(1), dim3(256), 0, stream, outS, rank_w, rank_b, out);
}